// Round 2
// baseline (722.536 us; speedup 1.0000x reference)
//
#include <hip/hip_runtime.h>
#include <stdint.h>

#define BDIM 32
#define CDIM 32
#define LDIM 1024
#define VDIM 4096
#define BCL (BDIM*CDIM*LDIM)
#define LT 64   // fuse l-tile

// ---------------------------------------------------------------- init
// f_rest=f, f_hat=0, e_sq, transposed phi weights, loss=0
__global__ void init_kernel(const float* __restrict__ f, const float* __restrict__ emb,
                            const float* __restrict__ phiw,
                            float* __restrict__ f_rest, float* __restrict__ f_hat,
                            float* __restrict__ e_sq, float* __restrict__ w_t,
                            float* __restrict__ loss_acc) {
    int i = blockIdx.x * blockDim.x + threadIdx.x;
    if (i < BCL) { f_rest[i] = f[i]; f_hat[i] = 0.0f; }
    if (i < VDIM) {
        const float4* e4 = (const float4*)(emb + (size_t)i * CDIM);
        float s = 0.f;
#pragma unroll
        for (int k = 0; k < 8; ++k) {
            float4 v = e4[k];
            s += v.x*v.x; s += v.y*v.y; s += v.z*v.z; s += v.w*v.w;
        }
        e_sq[i] = s;
    }
    if (i < 4 * 96 * 32) {
        int p  = i / 3072;
        int r  = i - p * 3072;
        int ik = r >> 5;
        int o  = r & 31;
        w_t[i] = phiw[p * 3072 + o * 96 + ik];   // [p][ik][o] <- [p][o][ik]
    }
    if (i == 0) *loss_acc = 0.f;
}

// ---------------------------------------------------------------- VQ stage 1
// One lane owns 2 queries (z in VGPRs). Codebook rows are wave-uniform ->
// scalar loads (SMEM pipe), FMAs use the 1-SGPR-operand slot. No LDS, no
// barriers, no atomics: each (query-group, v-chunk) wave writes its best
// (d,idx) packed u64 to cand[chunk][q]; the fuse kernel reduces chunks.
__device__ __forceinline__ void load_z(const float* __restrict__ fr, int q, int lpl,
                                       float* z, float& zz) {
    int b = q >> lpl;
    int j = q & ((1 << lpl) - 1);
    zz = 0.f;
    if (lpl == 10) {
        const float* base = fr + b * (CDIM * LDIM) + j;
#pragma unroll
        for (int c = 0; c < 32; ++c) { float v = base[c << 10]; z[c] = v; zz = fmaf(v, v, zz); }
    } else {
        // pos = (j+0.5)*s - 0.5, s = 2^(10-lpl) >= 4 -> lo = j*s + s/2 - 1, w = 0.5 exact
        int sh = 10 - lpl;
        int col = (j << sh) + (1 << (sh - 1)) - 1;
        const float* base = fr + b * (CDIM * LDIM) + col;
#pragma unroll
        for (int c = 0; c < 32; ++c) {
            float v = 0.5f * (base[c << 10] + base[(c << 10) + 1]);
            z[c] = v; zz = fmaf(v, v, zz);
        }
    }
}

__global__ __launch_bounds__(256) void vq1_kernel(
    const float* __restrict__ f_rest, const float* __restrict__ emb,
    const float* __restrict__ e_sq, unsigned long long* __restrict__ cand,
    int lpl, int NQ, int chunks, int CR, int total_waves)
{
    int wid  = (blockIdx.x * 256 + threadIdx.x) >> 6;
    int lane = threadIdx.x & 63;
    if (wid >= total_waves) return;
    int qg = wid / chunks;
    int vc = wid - qg * chunks;

    int q0 = qg * 128 + lane;
    int q1 = q0 + 64;
    int qc0 = min(q0, NQ - 1);
    int qc1 = min(q1, NQ - 1);

    float z0[32], z1[32], zz0, zz1;
    load_z(f_rest, qc0, lpl, z0, zz0);
    load_z(f_rest, qc1, lpl, z1, zz1);

    const int vbase = vc * CR;
    float bd0 = 3.4e38f, bd1 = 3.4e38f;
    int   bv0 = 0,       bv1 = 0;

    for (int r = 0; r < CR; r += 2) {
        const float* __restrict__ e0 = emb + (size_t)(vbase + r) * CDIM;  // uniform
        float es0 = e_sq[vbase + r];
        float es1 = e_sq[vbase + r + 1];
        float d00 = 0.f, d01 = 0.f, d10 = 0.f, d11 = 0.f;
#pragma unroll
        for (int c = 0; c < 32; ++c) {
            float ev0 = e0[c];        // scalar (wave-uniform) load
            float ev1 = e0[32 + c];
            d00 = fmaf(ev0, z0[c], d00);
            d01 = fmaf(ev0, z1[c], d01);
            d10 = fmaf(ev1, z0[c], d10);
            d11 = fmaf(ev1, z1[c], d11);
        }
        float A0 = fmaxf(fmaf(-2.f, d00, zz0 + es0), 0.f);
        float A1 = fmaxf(fmaf(-2.f, d01, zz1 + es0), 0.f);
        float B0 = fmaxf(fmaf(-2.f, d10, zz0 + es1), 0.f);
        float B1 = fmaxf(fmaf(-2.f, d11, zz1 + es1), 0.f);
        if (A0 < bd0) { bd0 = A0; bv0 = vbase + r; }
        if (B0 < bd0) { bd0 = B0; bv0 = vbase + r + 1; }
        if (A1 < bd1) { bd1 = A1; bv1 = vbase + r; }
        if (B1 < bd1) { bd1 = B1; bv1 = vbase + r + 1; }
    }

    unsigned long long k0 = ((unsigned long long)__float_as_uint(bd0) << 32) | (unsigned)bv0;
    unsigned long long k1 = ((unsigned long long)__float_as_uint(bd1) << 32) | (unsigned)bv1;
    if (q0 < NQ) cand[(size_t)vc * NQ + q0] = k0;
    if (q1 < NQ) cand[(size_t)vc * NQ + q1] = k1;
}

// ---------------------------------------------------------------- fused reduce+gather+upsample+phi+update+loss
__global__ __launch_bounds__(256) void fuse_kernel(
    const float* __restrict__ f, const float* __restrict__ emb,
    const unsigned long long* __restrict__ cand,
    const float* __restrict__ w_t, const float* __restrict__ bias,
    float* __restrict__ f_rest, float* __restrict__ f_hat,
    float* __restrict__ loss_acc, int lpl, int chunks, int NQ)
{
    const int t  = threadIdx.x;
    const int b  = blockIdx.y;
    const int l0 = blockIdx.x * LT;

    __shared__ float w_s[96 * 32];       // [ik][o] — conflict-free per-o reads
    __shared__ float b_s[32];
    __shared__ float hs[32 * 68];        // [i][66 cols + pad]; col x -> l = l0-1+x
    __shared__ float red[4];

    for (int x = t; x < 3072; x += 256) w_s[x] = w_t[x];
    if (t < 32) b_s[t] = bias[t];

    if (t < LT + 2) {
        int l = l0 - 1 + t;
        if (l < 0 || l >= LDIM) {
#pragma unroll
            for (int i = 0; i < 32; ++i) hs[i * 68 + t] = 0.f;
        } else {
            int pl = 1 << lpl;
            int lo, hi; float wg;
            if (lpl == 10) { lo = l; hi = l; wg = 0.f; }
            else {
                float pos = (l + 0.5f) * ((float)pl / 1024.0f) - 0.5f;
                pos = fminf(fmaxf(pos, 0.f), (float)(pl - 1));
                lo = (int)floorf(pos);
                hi = min(lo + 1, pl - 1);
                wg = pos - (float)lo;
            }
            unsigned long long k0 = ~0ull, k1 = ~0ull;
            const unsigned long long* c0 = cand + b * pl + lo;
            const unsigned long long* c1 = cand + b * pl + hi;
            for (int vc = 0; vc < chunks; ++vc) {
                k0 = min(k0, c0[(size_t)vc * NQ]);
                k1 = min(k1, c1[(size_t)vc * NQ]);
            }
            int v0 = (int)(k0 & 0xFFFFFFFFull);
            int v1 = (int)(k1 & 0xFFFFFFFFull);
            const float4* e0 = (const float4*)(emb + (size_t)v0 * 32);
            const float4* e1 = (const float4*)(emb + (size_t)v1 * 32);
            float om = 1.0f - wg;
#pragma unroll
            for (int i4 = 0; i4 < 8; ++i4) {
                float4 a = e0[i4]; float4 c = e1[i4];
                hs[(i4*4+0) * 68 + t] = a.x * om + c.x * wg;
                hs[(i4*4+1) * 68 + t] = a.y * om + c.y * wg;
                hs[(i4*4+2) * 68 + t] = a.z * om + c.z * wg;
                hs[(i4*4+3) * 68 + t] = a.w * om + c.w * wg;
            }
        }
    }
    __syncthreads();

    // conv: o = t>>3 (8 lanes broadcast same o, consecutive o -> no conflict),
    // sub = t&7 -> 8 consecutive l per thread (coalesced epilogue)
    const int o   = t >> 3;
    const int sub = t & 7;
    float acc[8];
#pragma unroll
    for (int u = 0; u < 8; ++u) acc[u] = 0.f;
    const int hbase = sub * 8;           // col x for l = l0 + sub*8 - 1

    for (int i = 0; i < 32; ++i) {
        float w0 = w_s[(i * 3 + 0) * 32 + o];
        float w1 = w_s[(i * 3 + 1) * 32 + o];
        float w2 = w_s[(i * 3 + 2) * 32 + o];
        const float* hr = &hs[i * 68 + hbase];
        float hw[10];
#pragma unroll
        for (int x = 0; x < 10; ++x) hw[x] = hr[x];
#pragma unroll
        for (int u = 0; u < 8; ++u) {
            acc[u] = fmaf(w0, hw[u],     acc[u]);
            acc[u] = fmaf(w1, hw[u + 1], acc[u]);
            acc[u] = fmaf(w2, hw[u + 2], acc[u]);
        }
    }

    float lsum = 0.f;
    const int gbase = (b * 32 + o) * LDIM + l0 + sub * 8;
#pragma unroll
    for (int u = 0; u < 8; ++u) {
        float hval = hs[o * 68 + sub * 8 + 1 + u];
        float y  = acc[u] + b_s[o];
        float ph = 0.5f * hval + 0.5f * y;   // RESI = 0.5
        int gi = gbase + u;
        float fh = f_hat[gi] + ph;
        f_hat[gi] = fh;
        f_rest[gi] -= ph;
        float df = fh - f[gi];
        lsum = fmaf(df, df, lsum);
    }

#pragma unroll
    for (int off = 32; off > 0; off >>= 1) lsum += __shfl_down(lsum, off, 64);
    if ((t & 63) == 0) red[t >> 6] = lsum;
    __syncthreads();
    if (t == 0) atomicAdd(loss_acc, red[0] + red[1] + red[2] + red[3]);
}

// ---------------------------------------------------------------- loss finalize
__global__ void final_kernel(const float* __restrict__ loss_acc, float* __restrict__ out_loss) {
    *out_loss = (*loss_acc) * (1.25f / (6.0f * (float)BCL));
}

// ---------------------------------------------------------------- launch
extern "C" void kernel_launch(void* const* d_in, const int* in_sizes, int n_in,
                              void* d_out, int out_size, void* d_ws, size_t ws_size,
                              hipStream_t stream)
{
    const float* f    = (const float*)d_in[0];
    const float* emb  = (const float*)d_in[1];
    const float* phiw = (const float*)d_in[2];
    const float* phib = (const float*)d_in[3];

    float* f_hat    = (float*)d_out;
    float* out_loss = f_hat + BCL;

    char* ws = (char*)d_ws;
    float* f_rest            = (float*)ws;                             // 4 MB
    float* e_sq              = (float*)(ws + (size_t)BCL * 4);         // 16 KB
    float* w_t               = e_sq + VDIM;                            // 48 KB
    float* loss_acc          = w_t + 4 * 96 * 32;
    unsigned long long* cand = (unsigned long long*)(ws + (size_t)BCL * 4 + 80 * 1024);

    size_t cand_avail = (ws_size > (size_t)BCL * 4 + 80 * 1024)
                      ? ws_size - ((size_t)BCL * 4 + 80 * 1024) : 0;

    init_kernel<<<dim3((BCL + 255) / 256), 256, 0, stream>>>(
        f, emb, phiw, f_rest, f_hat, e_sq, w_t, loss_acc);

    const int lpls[6] = {0, 2, 4, 6, 8, 10};
    const int crs[6]  = {64, 64, 64, 64, 128, 256};   // v-rows per chunk (pref)
    const int pidx[6] = {0, 0, 1, 2, 3, 3};

    for (int si = 0; si < 6; ++si) {
        int lpl = lpls[si];
        int pl  = 1 << lpl;
        int NQ  = BDIM * pl;
        int CR  = crs[si];
        int chunks = VDIM / CR;
        while ((size_t)chunks * NQ * 8 > cand_avail && chunks > 1) { chunks >>= 1; CR <<= 1; }
        int groups = (NQ + 127) / 128;
        int total_waves = groups * chunks;
        int blocks = (total_waves + 3) / 4;

        vq1_kernel<<<dim3(blocks), 256, 0, stream>>>(
            f_rest, emb, e_sq, cand, lpl, NQ, chunks, CR, total_waves);
        fuse_kernel<<<dim3(LDIM / LT, BDIM), 256, 0, stream>>>(
            f, emb, cand, w_t + (size_t)pidx[si] * 3072, phib + (size_t)pidx[si] * 32,
            f_rest, f_hat, loss_acc, lpl, chunks, NQ);
    }
    final_kernel<<<1, 1, 0, stream>>>(loss_acc, out_loss);
}

// Round 3
// 476.797 us; speedup vs baseline: 1.5154x; 1.5154x over previous
//
#include <hip/hip_runtime.h>
#include <stdint.h>

#define BDIM 32
#define CDIM 32
#define LDIM 1024
#define VDIM 4096
#define BCL (BDIM*CDIM*LDIM)
#define LT 64    // fuse l-tile
#define TR 256   // vq emb rows per LDS tile

// ---------------------------------------------------------------- init
__global__ void init_kernel(const float* __restrict__ f, const float* __restrict__ emb,
                            const float* __restrict__ phiw,
                            float* __restrict__ f_rest, float* __restrict__ f_hat,
                            float* __restrict__ e_sq, float* __restrict__ w_t,
                            float* __restrict__ loss_acc) {
    int i = blockIdx.x * blockDim.x + threadIdx.x;
    if (i < BCL) { f_rest[i] = f[i]; f_hat[i] = 0.0f; }
    if (i < VDIM) {
        const float4* e4 = (const float4*)(emb + (size_t)i * CDIM);
        float s = 0.f;
#pragma unroll
        for (int k = 0; k < 8; ++k) {
            float4 v = e4[k];
            s += v.x*v.x; s += v.y*v.y; s += v.z*v.z; s += v.w*v.w;
        }
        e_sq[i] = s;
    }
    if (i < 4 * 96 * 32) {
        int p  = i / 3072;
        int r  = i - p * 3072;
        int ik = r >> 5;
        int o  = r & 31;
        w_t[i] = phiw[p * 3072 + o * 96 + ik];   // [p][ik][o] <- [p][o][ik]
    }
    if (i == 0) *loss_acc = 0.f;
}

// ---------------------------------------------------------------- VQ
// lane = query (z in 32 VGPRs). Codebook tile staged in LDS; the emb row
// index is wave-uniform -> every ds_read_b128 is a same-address BROADCAST
// (no bank pressure, ~free). 4 rows in flight for FMA ILP. V-split across
// blocks (block-uniform), merged via packed (d,idx) u64 atomicMin so equal-d
// ties resolve to the lower index (argmin first-min rule).
__device__ __forceinline__ void load_z(const float* __restrict__ fr, int q, int lpl,
                                       float* z, float& zz) {
    int b = q >> lpl;
    int j = q & ((1 << lpl) - 1);
    zz = 0.f;
    if (lpl == 10) {
        const float* base = fr + b * (CDIM * LDIM) + j;
#pragma unroll
        for (int c = 0; c < 32; ++c) { float v = base[c << 10]; z[c] = v; zz = fmaf(v, v, zz); }
    } else {
        // s = 2^(10-lpl) >= 4 -> interp weight is exactly 0.5 at lo = j*s + s/2 - 1
        int sh = 10 - lpl;
        int col = (j << sh) + (1 << (sh - 1)) - 1;
        const float* base = fr + b * (CDIM * LDIM) + col;
#pragma unroll
        for (int c = 0; c < 32; ++c) {
            float v = 0.5f * (base[c << 10] + base[(c << 10) + 1]);
            z[c] = v; zz = fmaf(v, v, zz);
        }
    }
}

__global__ __launch_bounds__(256) void vq_kernel(
    const float* __restrict__ f_rest, const float* __restrict__ emb,
    const float* __restrict__ e_sq, unsigned long long* __restrict__ keys,
    int lpl, int NQ, int vsplit, int CR)
{
    const int t  = threadIdx.x;
    const int qb = blockIdx.x / vsplit;   // query block      (block-uniform)
    const int vc = blockIdx.x % vsplit;   // codebook chunk   (block-uniform)

    __shared__ float4 et[TR * 8];   // emb tile [r][c4]
    __shared__ float  es[TR];

    const int q  = qb * 256 + t;
    const int qc = min(q, NQ - 1);
    float z[32], zz;
    load_z(f_rest, qc, lpl, z, zz);

    float bd = 3.4e38f;
    int   bv = 0;
    const int vbase = vc * CR;

    for (int tb = 0; tb < CR; tb += TR) {
        const int rows = min(TR, CR - tb);        // CR is pow2 >= 8
        const float4* g = (const float4*)(emb + (size_t)(vbase + tb) * CDIM);
        for (int x = t; x < rows * 8; x += 256) et[x] = g[x];
        for (int x = t; x < rows;     x += 256) es[x] = e_sq[vbase + tb + x];
        __syncthreads();

        for (int r = 0; r < rows; r += 4) {
            float d0 = 0.f, d1 = 0.f, d2 = 0.f, d3 = 0.f;
#pragma unroll
            for (int c4 = 0; c4 < 8; ++c4) {
                float4 e0 = et[(r + 0) * 8 + c4];   // broadcast reads
                float4 e1 = et[(r + 1) * 8 + c4];
                float4 e2 = et[(r + 2) * 8 + c4];
                float4 e3 = et[(r + 3) * 8 + c4];
                d0 = fmaf(e0.x, z[4*c4+0], d0);
                d0 = fmaf(e0.y, z[4*c4+1], d0);
                d0 = fmaf(e0.z, z[4*c4+2], d0);
                d0 = fmaf(e0.w, z[4*c4+3], d0);
                d1 = fmaf(e1.x, z[4*c4+0], d1);
                d1 = fmaf(e1.y, z[4*c4+1], d1);
                d1 = fmaf(e1.z, z[4*c4+2], d1);
                d1 = fmaf(e1.w, z[4*c4+3], d1);
                d2 = fmaf(e2.x, z[4*c4+0], d2);
                d2 = fmaf(e2.y, z[4*c4+1], d2);
                d2 = fmaf(e2.z, z[4*c4+2], d2);
                d2 = fmaf(e2.w, z[4*c4+3], d2);
                d3 = fmaf(e3.x, z[4*c4+0], d3);
                d3 = fmaf(e3.y, z[4*c4+1], d3);
                d3 = fmaf(e3.z, z[4*c4+2], d3);
                d3 = fmaf(e3.w, z[4*c4+3], d3);
            }
            float A0 = fmaxf(fmaf(-2.f, d0, zz + es[r + 0]), 0.f);
            float A1 = fmaxf(fmaf(-2.f, d1, zz + es[r + 1]), 0.f);
            float A2 = fmaxf(fmaf(-2.f, d2, zz + es[r + 2]), 0.f);
            float A3 = fmaxf(fmaf(-2.f, d3, zz + es[r + 3]), 0.f);
            int vr = vbase + tb + r;
            if (A0 < bd) { bd = A0; bv = vr + 0; }
            if (A1 < bd) { bd = A1; bv = vr + 1; }
            if (A2 < bd) { bd = A2; bv = vr + 2; }
            if (A3 < bd) { bd = A3; bv = vr + 3; }
        }
        __syncthreads();
    }

    if (q < NQ) {
        unsigned long long key = ((unsigned long long)__float_as_uint(bd) << 32) | (unsigned)bv;
        atomicMin(&keys[q], key);
    }
}

// ---------------------------------------------------------------- fused gather+upsample+phi+update+loss
__global__ __launch_bounds__(256) void fuse_kernel(
    const float* __restrict__ f, const float* __restrict__ emb,
    const unsigned long long* __restrict__ keys,
    const float* __restrict__ w_t, const float* __restrict__ bias,
    float* __restrict__ f_rest, float* __restrict__ f_hat,
    float* __restrict__ loss_acc, int lpl)
{
    const int t  = threadIdx.x;
    const int b  = blockIdx.y;
    const int l0 = blockIdx.x * LT;

    __shared__ float w_s[96 * 32];       // [ik][o]
    __shared__ float b_s[32];
    __shared__ float hs[32 * 68];        // [i][66 cols + pad]
    __shared__ float red[4];

    for (int x = t; x < 3072; x += 256) w_s[x] = w_t[x];
    if (t < 32) b_s[t] = bias[t];

    if (t < LT + 2) {
        int l = l0 - 1 + t;
        if (l < 0 || l >= LDIM) {
#pragma unroll
            for (int i = 0; i < 32; ++i) hs[i * 68 + t] = 0.f;
        } else {
            int pl = 1 << lpl;
            int lo, hi; float wg;
            if (lpl == 10) { lo = l; hi = l; wg = 0.f; }
            else {
                float pos = (l + 0.5f) * ((float)pl / 1024.0f) - 0.5f;
                pos = fminf(fmaxf(pos, 0.f), (float)(pl - 1));
                lo = (int)floorf(pos);
                hi = min(lo + 1, pl - 1);
                wg = pos - (float)lo;
            }
            int v0 = (int)(keys[b * pl + lo] & 0xFFFFFFFFull);
            int v1 = (int)(keys[b * pl + hi] & 0xFFFFFFFFull);
            const float4* e0 = (const float4*)(emb + (size_t)v0 * 32);
            const float4* e1 = (const float4*)(emb + (size_t)v1 * 32);
            float om = 1.0f - wg;
#pragma unroll
            for (int i4 = 0; i4 < 8; ++i4) {
                float4 a = e0[i4]; float4 c = e1[i4];
                hs[(i4*4+0) * 68 + t] = a.x * om + c.x * wg;
                hs[(i4*4+1) * 68 + t] = a.y * om + c.y * wg;
                hs[(i4*4+2) * 68 + t] = a.z * om + c.z * wg;
                hs[(i4*4+3) * 68 + t] = a.w * om + c.w * wg;
            }
        }
    }
    __syncthreads();

    const int o   = t >> 3;
    const int sub = t & 7;
    float acc[8];
#pragma unroll
    for (int u = 0; u < 8; ++u) acc[u] = 0.f;
    const int hbase = sub * 8;

    for (int i = 0; i < 32; ++i) {
        float w0 = w_s[(i * 3 + 0) * 32 + o];
        float w1 = w_s[(i * 3 + 1) * 32 + o];
        float w2 = w_s[(i * 3 + 2) * 32 + o];
        const float* hr = &hs[i * 68 + hbase];
        float hw[10];
#pragma unroll
        for (int x = 0; x < 10; ++x) hw[x] = hr[x];
#pragma unroll
        for (int u = 0; u < 8; ++u) {
            acc[u] = fmaf(w0, hw[u],     acc[u]);
            acc[u] = fmaf(w1, hw[u + 1], acc[u]);
            acc[u] = fmaf(w2, hw[u + 2], acc[u]);
        }
    }

    float lsum = 0.f;
    const int gbase = (b * 32 + o) * LDIM + l0 + sub * 8;
#pragma unroll
    for (int u = 0; u < 8; ++u) {
        float hval = hs[o * 68 + sub * 8 + 1 + u];
        float y  = acc[u] + b_s[o];
        float ph = 0.5f * hval + 0.5f * y;   // RESI = 0.5
        int gi = gbase + u;
        float fh = f_hat[gi] + ph;
        f_hat[gi] = fh;
        f_rest[gi] -= ph;
        float df = fh - f[gi];
        lsum = fmaf(df, df, lsum);
    }

#pragma unroll
    for (int off = 32; off > 0; off >>= 1) lsum += __shfl_down(lsum, off, 64);
    if ((t & 63) == 0) red[t >> 6] = lsum;
    __syncthreads();
    if (t == 0) atomicAdd(loss_acc, red[0] + red[1] + red[2] + red[3]);
}

// ---------------------------------------------------------------- loss finalize
__global__ void final_kernel(const float* __restrict__ loss_acc, float* __restrict__ out_loss) {
    *out_loss = (*loss_acc) * (1.25f / (6.0f * (float)BCL));
}

// ---------------------------------------------------------------- launch
extern "C" void kernel_launch(void* const* d_in, const int* in_sizes, int n_in,
                              void* d_out, int out_size, void* d_ws, size_t ws_size,
                              hipStream_t stream)
{
    const float* f    = (const float*)d_in[0];
    const float* emb  = (const float*)d_in[1];
    const float* phiw = (const float*)d_in[2];
    const float* phib = (const float*)d_in[3];

    float* f_hat    = (float*)d_out;
    float* out_loss = f_hat + BCL;

    char* ws = (char*)d_ws;
    float* f_rest            = (float*)ws;                               // 4 MB
    float* e_sq              = (float*)(ws + (size_t)BCL * 4);           // 16 KB
    float* w_t               = e_sq + VDIM;                              // 48 KB
    float* loss_acc          = w_t + 4 * 96 * 32;
    unsigned long long* keys = (unsigned long long*)(ws + (size_t)BCL * 4 + 80 * 1024); // 256 KB

    init_kernel<<<dim3((BCL + 255) / 256), 256, 0, stream>>>(
        f, emb, phiw, f_rest, f_hat, e_sq, w_t, loss_acc);

    const int lpls[6] = {0, 2, 4, 6, 8, 10};
    const int vss[6]  = {64, 64, 64, 64, 16, 4};   // V-split per scale (~512 blocks)
    const int pidx[6] = {0, 0, 1, 2, 3, 3};

    for (int si = 0; si < 6; ++si) {
        int lpl = lpls[si];
        int pl  = 1 << lpl;
        int NQ  = BDIM * pl;
        int vs  = vss[si];
        int CR  = VDIM / vs;
        int qb  = (NQ + 255) / 256;

        hipMemsetAsync(keys, 0xFF, (size_t)NQ * 8, stream);
        vq_kernel<<<dim3(qb * vs), 256, 0, stream>>>(
            f_rest, emb, e_sq, keys, lpl, NQ, vs, CR);
        fuse_kernel<<<dim3(LDIM / LT, BDIM), 256, 0, stream>>>(
            f, emb, keys, w_t + (size_t)pidx[si] * 3072, phib + (size_t)pidx[si] * 32,
            f_rest, f_hat, loss_acc, lpl);
    }
    final_kernel<<<1, 1, 0, stream>>>(loss_acc, out_loss);
}

// Round 4
// 469.872 us; speedup vs baseline: 1.5377x; 1.0147x over previous
//
#include <hip/hip_runtime.h>
#include <stdint.h>

#define BDIM 32
#define CDIM 32
#define LDIM 1024
#define VDIM 4096
#define BCL (BDIM*CDIM*LDIM)
#define LT 64    // fuse l-tile
#define TR 256   // vq emb rows per LDS tile
#define NQTOT 43680  // 32 * (1+4+16+64+256+1024)

// ---------------------------------------------------------------- helpers
__device__ __forceinline__ unsigned ord_enc(float m) {
    // monotone float->uint map (works for any sign)
    unsigned u = __float_as_uint(m);
    return ((int)u >= 0) ? (u | 0x80000000u) : ~u;
}

// ---------------------------------------------------------------- init
// e_sq, transposed phi weights, zero ALL per-scale key slots, loss=0.
__global__ void init_kernel(const float* __restrict__ emb, const float* __restrict__ phiw,
                            float* __restrict__ e_sq, float* __restrict__ w_t,
                            unsigned long long* __restrict__ keys,
                            float* __restrict__ loss_acc) {
    int i = blockIdx.x * blockDim.x + threadIdx.x;
    if (i < VDIM) {
        const float4* e4 = (const float4*)(emb + (size_t)i * CDIM);
        float s = 0.f;
#pragma unroll
        for (int k = 0; k < 8; ++k) {
            float4 v = e4[k];
            s += v.x*v.x; s += v.y*v.y; s += v.z*v.z; s += v.w*v.w;
        }
        e_sq[i] = s;
    }
    if (i < 4 * 96 * 32) {
        int p  = i / 3072;
        int r  = i - p * 3072;
        int ik = r >> 5;
        int o  = r & 31;
        w_t[i] = phiw[p * 3072 + o * 96 + ik];   // [p][ik][o] <- [p][o][ik]
    }
    if (i < NQTOT) keys[i] = 0ull;
    if (i == 0) *loss_acc = 0.f;
}

// ---------------------------------------------------------------- VQ
// lane holds QPL queries (z in VGPRs) -> each broadcast LDS row-read feeds
// QPL*4 FMAs (LDS pipe no longer the bottleneck). argmin d == argmax
// m = dot - e^2/2 : accumulators start at -e^2/2 (staged), no per-row
// fixup VALU. Cross-chunk merge: atomicMax on (ord(m)<<32)|~idx so ties
// resolve to the smallest index (ref's first-min rule).
__device__ __forceinline__ void load_z(const float* __restrict__ fr, int q, int lpl,
                                       float* z) {
    int b = q >> lpl;
    int j = q & ((1 << lpl) - 1);
    if (lpl == 10) {
        const float* base = fr + b * (CDIM * LDIM) + j;
#pragma unroll
        for (int c = 0; c < 32; ++c) z[c] = base[c << 10];
    } else {
        // s = 2^(10-lpl) >= 4 -> downsample weight exactly 0.5 at col j*s + s/2 - 1
        int sh = 10 - lpl;
        int col = (j << sh) + (1 << (sh - 1)) - 1;
        const float* base = fr + b * (CDIM * LDIM) + col;
#pragma unroll
        for (int c = 0; c < 32; ++c)
            z[c] = 0.5f * (base[c << 10] + base[(c << 10) + 1]);
    }
}

template<int QPL>
__global__ __launch_bounds__(256) void vq_kernel(
    const float* __restrict__ src, const float* __restrict__ emb,
    const float* __restrict__ e_sq, unsigned long long* __restrict__ keys,
    int lpl, int NQ, int vsplit, int CR)
{
    const int t  = threadIdx.x;
    const int qb = blockIdx.x / vsplit;
    const int vc = blockIdx.x - qb * vsplit;

    __shared__ float4 et[TR * 8];
    __shared__ float  es2[TR];      // -e_sq/2

    float z[QPL][32];
    int   q[QPL];
#pragma unroll
    for (int k = 0; k < QPL; ++k) {
        q[k] = qb * (256 * QPL) + k * 256 + t;
        load_z(src, min(q[k], NQ - 1), lpl, z[k]);
    }

    float bm[QPL]; int bv[QPL];
#pragma unroll
    for (int k = 0; k < QPL; ++k) { bm[k] = -3.4e38f; bv[k] = 0; }

    const int vbase = vc * CR;
    for (int tb = 0; tb < CR; tb += TR) {
        const int rows = min(TR, CR - tb);
        const float4* g = (const float4*)(emb + (size_t)(vbase + tb) * CDIM);
        for (int x = t; x < rows * 8; x += 256) et[x] = g[x];
        for (int x = t; x < rows;     x += 256) es2[x] = -0.5f * e_sq[vbase + tb + x];
        __syncthreads();

        for (int r = 0; r < rows; r += 2) {
            float es0 = es2[r], es1 = es2[r + 1];
            float m0[QPL], m1[QPL];
#pragma unroll
            for (int k = 0; k < QPL; ++k) { m0[k] = es0; m1[k] = es1; }
#pragma unroll
            for (int c4 = 0; c4 < 8; ++c4) {
                float4 e0 = et[(r + 0) * 8 + c4];   // broadcast
                float4 e1 = et[(r + 1) * 8 + c4];
#pragma unroll
                for (int k = 0; k < QPL; ++k) {
                    m0[k] = fmaf(e0.x, z[k][4*c4+0], m0[k]);
                    m0[k] = fmaf(e0.y, z[k][4*c4+1], m0[k]);
                    m0[k] = fmaf(e0.z, z[k][4*c4+2], m0[k]);
                    m0[k] = fmaf(e0.w, z[k][4*c4+3], m0[k]);
                    m1[k] = fmaf(e1.x, z[k][4*c4+0], m1[k]);
                    m1[k] = fmaf(e1.y, z[k][4*c4+1], m1[k]);
                    m1[k] = fmaf(e1.z, z[k][4*c4+2], m1[k]);
                    m1[k] = fmaf(e1.w, z[k][4*c4+3], m1[k]);
                }
            }
            int vr = vbase + tb + r;
#pragma unroll
            for (int k = 0; k < QPL; ++k) {
                if (m0[k] > bm[k]) { bm[k] = m0[k]; bv[k] = vr; }
                if (m1[k] > bm[k]) { bm[k] = m1[k]; bv[k] = vr + 1; }
            }
        }
        __syncthreads();
    }

#pragma unroll
    for (int k = 0; k < QPL; ++k) {
        if (q[k] < NQ) {
            unsigned long long key =
                ((unsigned long long)ord_enc(bm[k]) << 32) | (unsigned)(~bv[k]);
            atomicMax(&keys[q[k]], key);
        }
    }
}

// ---------------------------------------------------------------- fused gather+upsample+phi+update+loss
__global__ __launch_bounds__(256) void fuse_kernel(
    const float* __restrict__ f, const float* __restrict__ emb,
    const unsigned long long* __restrict__ keys,
    const float* __restrict__ w_t, const float* __restrict__ bias,
    float* __restrict__ f_rest, float* __restrict__ f_hat,
    float* __restrict__ loss_acc, int lpl, int first, int last)
{
    const int t  = threadIdx.x;
    const int b  = blockIdx.y;
    const int l0 = blockIdx.x * LT;

    __shared__ float w_s[96 * 32];       // [ik][o]
    __shared__ float b_s[32];
    __shared__ float hs[32 * 68];        // [i][66 cols + pad]
    __shared__ float red[4];

    {   // weights: contiguous float4 copy
        const float4* w4 = (const float4*)w_t;
        float4* s4 = (float4*)w_s;
        for (int x = t; x < 768; x += 256) s4[x] = w4[x];
    }
    if (t < 32) b_s[t] = bias[t];

    {   // h staging: 2 threads per column (halves of the 32-channel vector)
        const int col  = t >> 1;
        const int half = t & 1;
        if (col < LT + 2) {
            int l = l0 - 1 + col;
            if (l < 0 || l >= LDIM) {
#pragma unroll
                for (int i4 = 0; i4 < 4; ++i4) {
                    int i = (half * 4 + i4) * 4;
                    hs[(i+0) * 68 + col] = 0.f;
                    hs[(i+1) * 68 + col] = 0.f;
                    hs[(i+2) * 68 + col] = 0.f;
                    hs[(i+3) * 68 + col] = 0.f;
                }
            } else {
                int pl = 1 << lpl;
                int lo, hi; float wg;
                if (lpl == 10) { lo = l; hi = l; wg = 0.f; }
                else {
                    float pos = (l + 0.5f) * ((float)pl / 1024.0f) - 0.5f;
                    pos = fminf(fmaxf(pos, 0.f), (float)(pl - 1));
                    lo = (int)floorf(pos);
                    hi = min(lo + 1, pl - 1);
                    wg = pos - (float)lo;
                }
                int v0 = ~(unsigned)(keys[b * pl + lo]);   // low word = ~idx
                int v1 = ~(unsigned)(keys[b * pl + hi]);
                const float4* e0 = (const float4*)(emb + (size_t)v0 * 32) + half * 4;
                const float4* e1 = (const float4*)(emb + (size_t)v1 * 32) + half * 4;
                float om = 1.0f - wg;
#pragma unroll
                for (int i4 = 0; i4 < 4; ++i4) {
                    float4 a = e0[i4]; float4 c = e1[i4];
                    int i = (half * 4 + i4) * 4;
                    hs[(i+0) * 68 + col] = a.x * om + c.x * wg;
                    hs[(i+1) * 68 + col] = a.y * om + c.y * wg;
                    hs[(i+2) * 68 + col] = a.z * om + c.z * wg;
                    hs[(i+3) * 68 + col] = a.w * om + c.w * wg;
                }
            }
        }
    }
    __syncthreads();

    const int o   = t >> 3;
    const int sub = t & 7;
    float acc[8];
#pragma unroll
    for (int u = 0; u < 8; ++u) acc[u] = 0.f;
    const int hbase = sub * 8;

    for (int i = 0; i < 32; ++i) {
        float w0 = w_s[(i * 3 + 0) * 32 + o];
        float w1 = w_s[(i * 3 + 1) * 32 + o];
        float w2 = w_s[(i * 3 + 2) * 32 + o];
        const float* hr = &hs[i * 68 + hbase];
        float hw[10];
#pragma unroll
        for (int x = 0; x < 10; ++x) hw[x] = hr[x];
#pragma unroll
        for (int u = 0; u < 8; ++u) {
            acc[u] = fmaf(w0, hw[u],     acc[u]);
            acc[u] = fmaf(w1, hw[u + 1], acc[u]);
            acc[u] = fmaf(w2, hw[u + 2], acc[u]);
        }
    }

    const int gbase = (b * 32 + o) * LDIM + l0 + sub * 8;
    float ph[8];
#pragma unroll
    for (int u = 0; u < 8; ++u) {
        float hval = hs[o * 68 + sub * 8 + 1 + u];
        ph[u] = 0.5f * hval + 0.5f * (acc[u] + b_s[o]);   // RESI = 0.5
    }

    const float4* fp  = (const float4*)(f + gbase);
    float4*       fhp = (float4*)(f_hat + gbase);
    float4*       frp = (float4*)(f_rest + gbase);
    float4 fa = fp[0], fb = fp[1];
    float4 h0, h1;
    if (first) { h0 = make_float4(0,0,0,0); h1 = make_float4(0,0,0,0); }
    else       { h0 = fhp[0]; h1 = fhp[1]; }
    h0.x += ph[0]; h0.y += ph[1]; h0.z += ph[2]; h0.w += ph[3];
    h1.x += ph[4]; h1.y += ph[5]; h1.z += ph[6]; h1.w += ph[7];
    fhp[0] = h0; fhp[1] = h1;

    if (!last) {
        float4 r0, r1;
        if (first) {
            r0 = make_float4(fa.x - ph[0], fa.y - ph[1], fa.z - ph[2], fa.w - ph[3]);
            r1 = make_float4(fb.x - ph[4], fb.y - ph[5], fb.z - ph[6], fb.w - ph[7]);
        } else {
            r0 = frp[0]; r1 = frp[1];
            r0.x -= ph[0]; r0.y -= ph[1]; r0.z -= ph[2]; r0.w -= ph[3];
            r1.x -= ph[4]; r1.y -= ph[5]; r1.z -= ph[6]; r1.w -= ph[7];
        }
        frp[0] = r0; frp[1] = r1;
    }

    float lsum = 0.f;
    {
        float d;
        d = h0.x - fa.x; lsum = fmaf(d, d, lsum);
        d = h0.y - fa.y; lsum = fmaf(d, d, lsum);
        d = h0.z - fa.z; lsum = fmaf(d, d, lsum);
        d = h0.w - fa.w; lsum = fmaf(d, d, lsum);
        d = h1.x - fb.x; lsum = fmaf(d, d, lsum);
        d = h1.y - fb.y; lsum = fmaf(d, d, lsum);
        d = h1.z - fb.z; lsum = fmaf(d, d, lsum);
        d = h1.w - fb.w; lsum = fmaf(d, d, lsum);
    }

#pragma unroll
    for (int off = 32; off > 0; off >>= 1) lsum += __shfl_down(lsum, off, 64);
    if ((t & 63) == 0) red[t >> 6] = lsum;
    __syncthreads();
    if (t == 0) atomicAdd(loss_acc, red[0] + red[1] + red[2] + red[3]);
}

// ---------------------------------------------------------------- loss finalize
__global__ void final_kernel(const float* __restrict__ loss_acc, float* __restrict__ out_loss) {
    *out_loss = (*loss_acc) * (1.25f / (6.0f * (float)BCL));
}

// ---------------------------------------------------------------- launch
extern "C" void kernel_launch(void* const* d_in, const int* in_sizes, int n_in,
                              void* d_out, int out_size, void* d_ws, size_t ws_size,
                              hipStream_t stream)
{
    const float* f    = (const float*)d_in[0];
    const float* emb  = (const float*)d_in[1];
    const float* phiw = (const float*)d_in[2];
    const float* phib = (const float*)d_in[3];

    float* f_hat    = (float*)d_out;
    float* out_loss = f_hat + BCL;

    char* ws = (char*)d_ws;
    float* f_rest            = (float*)ws;                               // 4 MB
    float* e_sq              = (float*)(ws + (size_t)BCL * 4);           // 16 KB
    float* w_t               = e_sq + VDIM;                              // 48 KB
    float* loss_acc          = w_t + 4 * 96 * 32;
    unsigned long long* keys = (unsigned long long*)(ws + (size_t)BCL * 4 + 80 * 1024); // 349 KB

    init_kernel<<<dim3((NQTOT + 255) / 256), 256, 0, stream>>>(
        emb, phiw, e_sq, w_t, keys, loss_acc);

    const int lpls[6] = {0, 2, 4, 6, 8, 10};
    const int vss[6]  = {256, 256, 128, 128, 64, 16};
    const int koff[6] = {0, 32, 160, 672, 2720, 10912};
    const int pidx[6] = {0, 0, 1, 2, 3, 3};

    for (int si = 0; si < 6; ++si) {
        int lpl = lpls[si];
        int NQ  = BDIM << lpl;
        int vs  = vss[si];
        int CR  = VDIM / vs;
        const float* src = (si == 0) ? f : f_rest;
        unsigned long long* k = keys + koff[si];

        if (si >= 3) {
            int qb = (NQ + 1023) / 1024;
            vq_kernel<4><<<dim3(qb * vs), 256, 0, stream>>>(src, emb, e_sq, k, lpl, NQ, vs, CR);
        } else {
            int qb = (NQ + 255) / 256;
            vq_kernel<1><<<dim3(qb * vs), 256, 0, stream>>>(src, emb, e_sq, k, lpl, NQ, vs, CR);
        }
        fuse_kernel<<<dim3(LDIM / LT, BDIM), 256, 0, stream>>>(
            f, emb, k, w_t + (size_t)pidx[si] * 3072, phib + (size_t)pidx[si] * 32,
            f_rest, f_hat, loss_acc, lpl, si == 0, si == 5);
    }
    final_kernel<<<1, 1, 0, stream>>>(loss_acc, out_loss);
}